// Round 1
// baseline (438.945 us; speedup 1.0000x reference)
//
#include <hip/hip_runtime.h>
#include <hip/hip_bf16.h>
#include <stdint.h>

#define B_ 8
#define H_ 8
#define S_ 512
#define K_ 64
#define NMB_ 4
#define C_ 17
#define NG_ 5
#define RI_ 8
#define NTASK_ 68

// ---- workspace layout (bytes) ----
#define OFF_FLAG 0
#define OFF_PERM 256
#define OFF_TASKS (OFF_PERM + B_*S_*4)                       // 16640 (16B aligned)
#define OFF_W2S   (((OFF_TASKS + B_*NTASK_*16) + 255) & ~255) // 25344
#define OFF_STMP  (((OFF_W2S + C_*H_*K_*K_*4) + 255) & ~255)  // 2253568
// total = OFF_STMP + B_*H_*S_*NG_*K_*4  ~= 44.2 MB

__device__ __forceinline__ float bf2f(uint16_t u) {
    union { uint32_t i; float f; } x; x.i = ((uint32_t)u) << 16; return x.f;
}

// ---------------- dtype detector ----------------
// fp32 uniform[0,1): low 16 bits are random mantissa bits -> ~75% >= 0x4000.
// bf16 pairs of [0,1) values: low 16 bits are a bf16 pattern < 0x3F80 -> 0%.
__global__ void k_detect(const uint32_t* __restrict__ p, int* __restrict__ flag) {
    __shared__ int red[256];
    int t = threadIdx.x;
    int c = 0;
    for (int k = 0; k < 16; ++k) {
        uint32_t w = p[t * 16 + k];
        c += ((w & 0xFFFFu) >= 0x4000u) ? 1 : 0;
    }
    red[t] = c;
    __syncthreads();
    for (int s = 128; s > 0; s >>= 1) {
        if (t < s) red[t] += red[t + s];
        __syncthreads();
    }
    if (t == 0) flag[0] = red[0];   // >1024 => fp32, else bf16
}

// ---------------- per-b counting sort of rows by bi-class ----------------
__global__ void k_sort(const int* __restrict__ b_seq, int* __restrict__ perm,
                       int4* __restrict__ tasks) {
    const int b = blockIdx.x;
    const int lane = threadIdx.x;           // 64 threads = 1 wave
    const int* bs = b_seq + b * S_;

    int tot[NG_] = {0, 0, 0, 0, 0};
    for (int ch = 0; ch < S_ / 64; ++ch) {
        int g = bs[ch * 64 + lane];
        for (int bin = 0; bin < NG_; ++bin) {
            unsigned long long m = __ballot(g == bin);
            tot[bin] += (int)__popcll(m);
        }
    }
    int starts[NG_]; int run = 0;
    for (int bin = 0; bin < NG_; ++bin) { starts[bin] = run; run += tot[bin]; }

    int running[NG_] = {0, 0, 0, 0, 0};
    unsigned long long lt = (1ull << lane) - 1ull;
    for (int ch = 0; ch < S_ / 64; ++ch) {
        int i = ch * 64 + lane;
        int g = bs[i];
        int pos = 0;
        for (int bin = 0; bin < NG_; ++bin) {
            unsigned long long m = __ballot(g == bin);
            if (g == bin) pos = starts[bin] + running[bin] + (int)__popcll(m & lt);
            running[bin] += (int)__popcll(m);
        }
        perm[b * S_ + pos] = i;
    }
    if (lane == 0) {
        int t = 0;
        for (int bi = 0; bi < NG_; ++bi) {
            for (int o = 0; o < tot[bi]; o += RI_) {
                int n = tot[bi] - o; if (n > RI_) n = RI_;
                tasks[b * NTASK_ + t] = make_int4(bi, starts[bi] + o, n, 0);
                ++t;
            }
        }
        for (; t < NTASK_; ++t) tasks[b * NTASK_ + t] = make_int4(0, 0, 0, 0);
    }
}

// ---------------- W2_ = einsum('BhdD,CBh->ChdD', W2, softmax(alpha2,1)) ----------------
template<bool BF16>
__device__ __forceinline__ void w2s_impl(const void* __restrict__ W2,
                                         const void* __restrict__ alpha2,
                                         float* __restrict__ W2s) {
    const int c = blockIdx.x / H_, h = blockIdx.x % H_;
    float a[NMB_]; float mx = -1e30f;
#pragma unroll
    for (int m = 0; m < NMB_; ++m) {
        int idx = (c * NMB_ + m) * H_ + h;
        a[m] = BF16 ? bf2f(((const uint16_t*)alpha2)[idx]) : ((const float*)alpha2)[idx];
        mx = fmaxf(mx, a[m]);
    }
    float s = 0.f;
#pragma unroll
    for (int m = 0; m < NMB_; ++m) { a[m] = __expf(a[m] - mx); s += a[m]; }
    const float inv = 1.f / s;
#pragma unroll
    for (int m = 0; m < NMB_; ++m) a[m] *= inv;

    for (int e = threadIdx.x; e < K_ * K_; e += 256) {
        float acc = 0.f;
#pragma unroll
        for (int m = 0; m < NMB_; ++m) {
            int widx = (m * H_ + h) * (K_ * K_) + e;
            float w = BF16 ? bf2f(((const uint16_t*)W2)[widx]) : ((const float*)W2)[widx];
            acc += a[m] * w;
        }
        W2s[(c * H_ + h) * (K_ * K_) + e] = acc;
    }
}

__global__ void k_w2s(const void* __restrict__ W2, const void* __restrict__ alpha2,
                      const int* __restrict__ flag, float* __restrict__ W2s) {
    if (flag[0] > 1024) w2s_impl<false>(W2, alpha2, W2s);
    else                w2s_impl<true >(W2, alpha2, W2s);
}

// ---------------- stage 1: group-bucketed P.V -> stmp[b,h,i, g*64+d] ----------------
#define ACC_CASE(G, P, V) case G: _Pragma("unroll") \
    for (int r = 0; r < RI_; ++r) acc[r][G] += P[r] * V; break;

template<bool BF16>
__device__ __forceinline__ void stage1_impl(const void* __restrict__ pattn,
                                            const void* __restrict__ value,
                                            const int* __restrict__ b_seq,
                                            float* __restrict__ stmp) {
    const int b = blockIdx.z, h = blockIdx.y;
    const int wid = __builtin_amdgcn_readfirstlane((int)threadIdx.y); // wave id -> scalar
    const int i0 = blockIdx.x * (RI_ * 4) + wid * RI_;
    const int d = threadIdx.x;

    float acc[RI_][NG_];
#pragma unroll
    for (int r = 0; r < RI_; ++r)
#pragma unroll
        for (int g = 0; g < NG_; ++g) acc[r][g] = 0.f;

    const int pbase = ((b * H_ + h) * S_ + i0) * S_;   // element offset, wave-uniform
    const int vbase = (b * H_ + h) * S_ * K_;
    const int* bs = b_seq + b * S_;
    const float*    pf = (const float*)pattn;
    const uint32_t* pw = (const uint32_t*)pattn;
    const float*    vf = (const float*)value;
    const uint16_t* vh = (const uint16_t*)value;

    for (int j = 0; j < S_; j += 2) {
        const int g0 = bs[j];        // uniform index -> s_load; scalar switch below
        const int g1 = bs[j + 1];
        float v0, v1;
        if (BF16) {
            v0 = bf2f(vh[vbase + j * K_ + d]);
            v1 = bf2f(vh[vbase + (j + 1) * K_ + d]);
        } else {
            v0 = vf[vbase + j * K_ + d];
            v1 = vf[vbase + (j + 1) * K_ + d];
        }
        float p0[RI_], p1[RI_];
#pragma unroll
        for (int r = 0; r < RI_; ++r) {
            if (BF16) {
                uint32_t w = pw[(pbase + r * S_ + j) >> 1];   // uniform -> s_load_dword
                union { uint32_t i; float f; } lo, hi;
                lo.i = w << 16; hi.i = w & 0xFFFF0000u;
                p0[r] = lo.f; p1[r] = hi.f;
            } else {
                p0[r] = pf[pbase + r * S_ + j];               // uniform -> s_load
                p1[r] = pf[pbase + r * S_ + j + 1];
            }
        }
        switch (g0) { ACC_CASE(0,p0,v0) ACC_CASE(1,p0,v0) ACC_CASE(2,p0,v0)
                      ACC_CASE(3,p0,v0) ACC_CASE(4,p0,v0) }
        switch (g1) { ACC_CASE(0,p1,v1) ACC_CASE(1,p1,v1) ACC_CASE(2,p1,v1)
                      ACC_CASE(3,p1,v1) ACC_CASE(4,p1,v1) }
    }

    const int obase = ((b * H_ + h) * S_ + i0) * (NG_ * K_);
#pragma unroll
    for (int r = 0; r < RI_; ++r)
#pragma unroll
        for (int g = 0; g < NG_; ++g)
            stmp[obase + r * (NG_ * K_) + g * K_ + d] = acc[r][g];
}

__global__ __launch_bounds__(256) void k_stage1(const void* p, const void* v,
                                                const int* bs, const int* flag,
                                                float* stmp) {
    if (flag[0] > 1024) stage1_impl<false>(p, v, bs, stmp);
    else                stage1_impl<true >(p, v, bs, stmp);
}

// ---------------- stage 2: out[i,D] = stmp[i,:] @ Wstack[bi], rows sorted by bi ----------------
template<bool BF16>
__device__ __forceinline__ void stage2_impl(const float* __restrict__ stmp,
                                            const float* __restrict__ W2s,
                                            const int* __restrict__ perm,
                                            const int4* __restrict__ tasks,
                                            void* __restrict__ out) {
    const int b = blockIdx.z, h = blockIdx.y;
    const int wid = __builtin_amdgcn_readfirstlane((int)threadIdx.y);
    const int t = blockIdx.x * 4 + wid;
    const int4 tk = tasks[b * NTASK_ + t];   // uniform -> s_load
    const int bi = tk.x, off = tk.y, n = tk.z;
    if (n == 0) return;
    const int D = threadIdx.x;

    int irow[RI_]; int abase[RI_];
#pragma unroll
    for (int r = 0; r < RI_; ++r) {
        int pos = off + (r < n ? r : 0);     // clamp padded rows (computed, not stored)
        int i = perm[b * S_ + pos];          // uniform -> s_load
        irow[r] = i;
        abase[r] = ((b * H_ + h) * S_ + i) * (NG_ * K_);
    }
    float acc[RI_];
#pragma unroll
    for (int r = 0; r < RI_; ++r) acc[r] = 0.f;

    for (int g = 0; g < NG_; ++g) {
        const int c = (bi == 0 || g == 0) ? 0 : (bi - 1) * NMB_ + g;
        const float* wb = W2s + (c * H_ + h) * (K_ * K_);
#pragma unroll 8
        for (int d = 0; d < K_; ++d) {
            float w = wb[d * K_ + D];        // vector load, L1/L2-hot, shared by 8 rows
#pragma unroll
            for (int r = 0; r < RI_; ++r)
                acc[r] += stmp[abase[r] + g * K_ + d] * w;   // uniform -> s_load batches
        }
    }
#pragma unroll
    for (int r = 0; r < RI_; ++r) {
        if (r < n) {
            int oidx = ((b * H_ + h) * S_ + irow[r]) * K_ + D;
            if (BF16) ((__hip_bfloat16*)out)[oidx] = __float2bfloat16(acc[r]);
            else      ((float*)out)[oidx] = acc[r];
        }
    }
}

__global__ __launch_bounds__(256) void k_stage2(const float* stmp, const float* W2s,
                                                const int* perm, const int4* tasks,
                                                const int* flag, void* out) {
    if (flag[0] > 1024) stage2_impl<false>(stmp, W2s, perm, tasks, out);
    else                stage2_impl<true >(stmp, W2s, perm, tasks, out);
}

// ---------------- launcher ----------------
extern "C" void kernel_launch(void* const* d_in, const int* in_sizes, int n_in,
                              void* d_out, int out_size, void* d_ws, size_t ws_size,
                              hipStream_t stream) {
    const void* p_attn = d_in[0];
    const void* value  = d_in[1];
    const int*  b_seq  = (const int*)d_in[2];
    const void* W2     = d_in[3];
    const void* alpha2 = d_in[4];

    char* ws = (char*)d_ws;
    int*   flag  = (int*)(ws + OFF_FLAG);
    int*   perm  = (int*)(ws + OFF_PERM);
    int4*  tasks = (int4*)(ws + OFF_TASKS);
    float* W2s   = (float*)(ws + OFF_W2S);
    float* stmp  = (float*)(ws + OFF_STMP);

    hipLaunchKernelGGL(k_detect, dim3(1), dim3(256), 0, stream,
                       (const uint32_t*)p_attn, flag);
    hipLaunchKernelGGL(k_sort, dim3(B_), dim3(64), 0, stream, b_seq, perm, tasks);
    hipLaunchKernelGGL(k_w2s, dim3(C_ * H_), dim3(256), 0, stream,
                       W2, alpha2, flag, W2s);
    hipLaunchKernelGGL(k_stage1, dim3(S_ / (RI_ * 4), H_, B_), dim3(64, 4), 0, stream,
                       p_attn, value, b_seq, flag, stmp);
    hipLaunchKernelGGL(k_stage2, dim3(NTASK_ / 4, H_, B_), dim3(64, 4), 0, stream,
                       stmp, W2s, perm, tasks, flag, d_out);
}

// Round 5
// 207.913 us; speedup vs baseline: 2.1112x; 2.1112x over previous
//
#include <hip/hip_runtime.h>
#include <hip/hip_bf16.h>
#include <stdint.h>

#define B_ 8
#define H_ 8
#define S_ 512
#define K_ 64
#define NMB_ 4
#define NG_ 5

typedef unsigned short u16;
typedef __attribute__((ext_vector_type(8))) short short8;   // 8 x bf16 bits (4 VGPRs)
typedef __attribute__((ext_vector_type(4))) float f32x4;

// ---- workspace layout (bytes) ----
#define OFF_PERM 0                       // B_*S_*4 = 16 KB
#define OFF_WST  16384                   // H_*NG_*10*64*32*2 = 1.31 MB
#define OFF_MF   (1 << 21)               // 2 MB; M_frag: B_*H_*16*320*32*2 = 20.97 MB

__device__ __forceinline__ u16 f2b(float f) {
    __hip_bfloat16 h = __float2bfloat16(f);
    return *reinterpret_cast<u16*>(&h);
}
__device__ __forceinline__ short8 ld16(const u16* p) {
    return *reinterpret_cast<const short8*>(p);
}
__device__ __forceinline__ int clamp5(int g) {
    g = g < 0 ? 0 : g;
    return g > (NG_ - 1) ? (NG_ - 1) : g;
}

// ---------------- per-b counting sort of rows by b_seq class ----------------
__global__ void k_sort(const int* __restrict__ b_seq, int* __restrict__ perm) {
    const int b = blockIdx.x;
    const int lane = threadIdx.x;            // 64 threads = 1 wave
    const int* bs = b_seq + b * S_;

    int tot[NG_] = {0,0,0,0,0};
    for (int ch = 0; ch < S_ / 64; ++ch) {
        int g = clamp5(bs[ch * 64 + lane]);
        for (int bin = 0; bin < NG_; ++bin) {
            unsigned long long m = __ballot(g == bin);
            tot[bin] += (int)__popcll(m);
        }
    }
    int starts[NG_]; int run = 0;
    for (int bin = 0; bin < NG_; ++bin) { starts[bin] = run; run += tot[bin]; }

    int running[NG_] = {0,0,0,0,0};
    unsigned long long lt = (1ull << lane) - 1ull;
    for (int ch = 0; ch < S_ / 64; ++ch) {
        int i = ch * 64 + lane;
        int g = clamp5(bs[i]);
        int pos = 0;
        for (int bin = 0; bin < NG_; ++bin) {
            unsigned long long m = __ballot(g == bin);
            if (g == bin) pos = starts[bin] + running[bin] + (int)__popcll(m & lt);
            running[bin] += (int)__popcll(m);
        }
        perm[b * S_ + pos] = i;
    }
}

// ---- Wstack[h][bi][kt][D][kk] = W2_[c(bi,g),h,d,D], B-frag swizzled bf16; fp32 in ----
// k = g*64+d in [0,320), kt = k>>5, kk = k&31.
__global__ void k_w2s(const float* __restrict__ W2, const float* __restrict__ al,
                      u16* __restrict__ Wst) {
    const int h = blockIdx.x / NG_, bi = blockIdx.x % NG_;
    float sm[NG_][NMB_];
#pragma unroll
    for (int g = 0; g < NG_; ++g) {
        int c = (bi == 0 || g == 0) ? 0 : (bi - 1) * NMB_ + g;
        float a[NMB_]; float mx = -1e30f;
#pragma unroll
        for (int m = 0; m < NMB_; ++m) { a[m] = al[(c * NMB_ + m) * H_ + h]; mx = fmaxf(mx, a[m]); }
        float s = 0.f;
#pragma unroll
        for (int m = 0; m < NMB_; ++m) { a[m] = __expf(a[m] - mx); s += a[m]; }
        float inv = 1.f / s;
#pragma unroll
        for (int m = 0; m < NMB_; ++m) sm[g][m] = a[m] * inv;
    }
    for (int e = threadIdx.x; e < 320 * 64; e += 256) {
        int k = e >> 6, D = e & 63;
        int g = k >> 6, d = k & 63;
        float acc = 0.f;
#pragma unroll
        for (int m = 0; m < NMB_; ++m)
            acc += sm[g][m] * W2[((m * H_ + h) * K_ + d) * K_ + D];
        int kt = k >> 5, kk = k & 31;
        Wst[(((h * NG_ + bi) * 10 + kt) * 64 + D) * 32 + kk] = f2b(acc);
    }
}

// ---- M_frag[b][h][kt][n][kk] = (b_seq[j]==g ? v[j,d] : 0), B-frag swizzled bf16; fp32 in ----
// n = g*64+d in [0,320), j = kt*32+kk.
__global__ void k_buildM(const float* __restrict__ V, const int* __restrict__ b_seq,
                         u16* __restrict__ Mf) {
    const int kt = blockIdx.x, h = blockIdx.y, b = blockIdx.z;
    const int n = threadIdx.x;               // 0..319
    const int g = n >> 6, d = n & 63;
    const int bh = b * H_ + h;
    u16 o[32];
#pragma unroll
    for (int kk = 0; kk < 32; ++kk) {
        int j = kt * 32 + kk;
        int gj = clamp5(b_seq[b * S_ + j]);  // uniform -> s_load
        float v = V[((size_t)bh * S_ + j) * K_ + d];   // coalesced fp32
        o[kk] = (gj == g) ? f2b(v) : (u16)0;
    }
    uint4* dst = (uint4*)(Mf + (((size_t)bh * 16 + kt) * 320 + n) * 32);
#pragma unroll
    for (int t = 0; t < 4; ++t) {
        uint4 w;
        w.x = (uint32_t)o[t*8+0] | ((uint32_t)o[t*8+1] << 16);
        w.y = (uint32_t)o[t*8+2] | ((uint32_t)o[t*8+3] << 16);
        w.z = (uint32_t)o[t*8+4] | ((uint32_t)o[t*8+5] << 16);
        w.w = (uint32_t)o[t*8+6] | ((uint32_t)o[t*8+7] << 16);
        dst[t] = w;
    }
}

// ---- fused: stmp = P@M (MFMA) -> LDS -> out = stmp@Wstack[bi] (MFMA); fp32 P in, fp32 out ----
__global__ __launch_bounds__(256) void k_main(const float* __restrict__ P,
                                              const int* __restrict__ b_seq,
                                              const int* __restrict__ perm,
                                              const u16* __restrict__ Mf,
                                              const u16* __restrict__ Wst,
                                              float* __restrict__ out) {
    __shared__ __align__(16) u16 smem[4][16 * 328];  // per-wave 16x320 tile, +8 pad
    const int b = blockIdx.z, h = blockIdx.y;
    const int w = threadIdx.y;
    const int lane = threadIdx.x;
    const int r16 = lane & 15, quad = lane >> 4;
    const int tile = blockIdx.x * 4 + w;             // 0..31
    const int bh = b * H_ + h;

    // gathered rows (sorted by bi); lane L holds row L&15
    const int vi  = perm[b * S_ + tile * 16 + r16] & (S_ - 1);
    const int vbi = clamp5(b_seq[b * S_ + vi]);

    // ---- stage 1: acc1[nt] (16 x 320) = P[rows, :] @ M ----
    f32x4 acc1[20];
#pragma unroll
    for (int nt = 0; nt < 20; ++nt) acc1[nt] = (f32x4){0.f, 0.f, 0.f, 0.f};

    // A[m=r16][k = kt*32 + quad*8 + j], fp32 -> bf16 cvt in-register
    const float* aP = P + ((size_t)bh * S_ + vi) * S_ + quad * 8;
    for (int kt = 0; kt < 16; ++kt) {
        float4 x = *reinterpret_cast<const float4*>(aP + kt * 32);
        float4 y = *reinterpret_cast<const float4*>(aP + kt * 32 + 4);
        short8 afrag;
        afrag[0] = (short)f2b(x.x); afrag[1] = (short)f2b(x.y);
        afrag[2] = (short)f2b(x.z); afrag[3] = (short)f2b(x.w);
        afrag[4] = (short)f2b(y.x); afrag[5] = (short)f2b(y.y);
        afrag[6] = (short)f2b(y.z); afrag[7] = (short)f2b(y.w);
        const u16* mb = Mf + (((size_t)bh * 16 + kt) * 320 + r16) * 32 + quad * 8;
#pragma unroll
        for (int nt = 0; nt < 20; ++nt) {
            short8 bfrag = ld16(mb + (size_t)nt * 16 * 32);
            acc1[nt] = __builtin_amdgcn_mfma_f32_16x16x32_bf16(afrag, bfrag, acc1[nt], 0, 0, 0);
        }
    }

    // ---- C-layout -> A-layout via LDS (bf16 cast) ----
    u16* st = smem[w];
#pragma unroll
    for (int nt = 0; nt < 20; ++nt)
#pragma unroll
        for (int r = 0; r < 4; ++r) {
            int row = quad * 4 + r;                  // C/D: row=(lane>>4)*4+reg, col=lane&15
            st[row * 328 + nt * 16 + r16] = f2b(acc1[nt][r]);
        }
    __syncthreads();

    // ---- stage 2: out rows = stmp_tile @ Wstack[blk], only blocks present in tile ----
    int blo = __shfl(vbi, 0), bhi = __shfl(vbi, 15);   // sorted => contiguous classes
    if (bhi < blo) bhi = blo;
    for (int blk = blo; blk <= bhi; ++blk) {
        f32x4 acc2[4];
#pragma unroll
        for (int nt = 0; nt < 4; ++nt) acc2[nt] = (f32x4){0.f, 0.f, 0.f, 0.f};
        const u16* wb = Wst + ((size_t)(h * NG_ + blk) * 10) * (64 * 32) + r16 * 32 + quad * 8;
        for (int kt = 0; kt < 10; ++kt) {
            short8 a2 = *reinterpret_cast<const short8*>(&st[r16 * 328 + kt * 32 + quad * 8]);
#pragma unroll
            for (int nt = 0; nt < 4; ++nt) {
                short8 b2 = ld16(wb + kt * (64 * 32) + nt * 16 * 32);
                acc2[nt] = __builtin_amdgcn_mfma_f32_16x16x32_bf16(a2, b2, acc2[nt], 0, 0, 0);
            }
        }
#pragma unroll
        for (int r = 0; r < 4; ++r) {
            int row = quad * 4 + r;
            int bir = __shfl(vbi, row);
            int ir  = __shfl(vi, row);
            if (bir == blk) {
#pragma unroll
                for (int nt = 0; nt < 4; ++nt)
                    out[((size_t)bh * S_ + ir) * K_ + nt * 16 + r16] = acc2[nt][r];
            }
        }
    }
}

// ---------------- launcher ----------------
extern "C" void kernel_launch(void* const* d_in, const int* in_sizes, int n_in,
                              void* d_out, int out_size, void* d_ws, size_t ws_size,
                              hipStream_t stream) {
    const float* p_attn = (const float*)d_in[0];
    const float* value  = (const float*)d_in[1];
    const int*   b_seq  = (const int*)d_in[2];
    const float* W2     = (const float*)d_in[3];
    const float* alpha2 = (const float*)d_in[4];

    char* ws = (char*)d_ws;
    int* perm = (int*)(ws + OFF_PERM);
    u16* Wst  = (u16*)(ws + OFF_WST);
    u16* Mf   = (u16*)(ws + OFF_MF);

    hipLaunchKernelGGL(k_sort, dim3(B_), dim3(64), 0, stream, b_seq, perm);
    hipLaunchKernelGGL(k_w2s, dim3(H_ * NG_), dim3(256), 0, stream, W2, alpha2, Wst);
    hipLaunchKernelGGL(k_buildM, dim3(16, H_, B_), dim3(320), 0, stream, value, b_seq, Mf);
    hipLaunchKernelGGL(k_main, dim3(8, H_, B_), dim3(64, 4), 0, stream,
                       p_attn, b_seq, perm, Mf, Wst, (float*)d_out);
}

// Round 6
// 201.837 us; speedup vs baseline: 2.1747x; 1.0301x over previous
//
#include <hip/hip_runtime.h>
#include <hip/hip_bf16.h>
#include <stdint.h>

#define B_ 8
#define H_ 8
#define S_ 512
#define K_ 64
#define NMB_ 4
#define NG_ 5

typedef unsigned short u16;
typedef __attribute__((ext_vector_type(8))) short short8;   // 8 x bf16 bits (4 VGPRs)
typedef __attribute__((ext_vector_type(4))) float f32x4;

// ---- workspace layout (bytes) ----
#define OFF_PERM 0                       // B_*S_*4 = 16 KB
#define OFF_WST  16384                   // H_*NG_*10*64*32*2 = 1.31 MB
#define OFF_MF   (1 << 21)               // 2 MB; M_frag: B_*H_*16*320*32*2 = 20.97 MB

__device__ __forceinline__ u16 f2b(float f) {
    __hip_bfloat16 h = __float2bfloat16(f);
    return *reinterpret_cast<u16*>(&h);
}
__device__ __forceinline__ short8 ld16(const u16* p) {
    return *reinterpret_cast<const short8*>(p);
}
__device__ __forceinline__ int clamp5(int g) {
    g = g < 0 ? 0 : g;
    return g > (NG_ - 1) ? (NG_ - 1) : g;
}

// ---------------- per-b counting sort of rows by b_seq class ----------------
__global__ void k_sort(const int* __restrict__ b_seq, int* __restrict__ perm) {
    const int b = blockIdx.x;
    const int lane = threadIdx.x;            // 64 threads = 1 wave
    const int* bs = b_seq + b * S_;

    int tot[NG_] = {0,0,0,0,0};
    for (int ch = 0; ch < S_ / 64; ++ch) {
        int g = clamp5(bs[ch * 64 + lane]);
        for (int bin = 0; bin < NG_; ++bin) {
            unsigned long long m = __ballot(g == bin);
            tot[bin] += (int)__popcll(m);
        }
    }
    int starts[NG_]; int run = 0;
    for (int bin = 0; bin < NG_; ++bin) { starts[bin] = run; run += tot[bin]; }

    int running[NG_] = {0,0,0,0,0};
    unsigned long long lt = (1ull << lane) - 1ull;
    for (int ch = 0; ch < S_ / 64; ++ch) {
        int i = ch * 64 + lane;
        int g = clamp5(bs[i]);
        int pos = 0;
        for (int bin = 0; bin < NG_; ++bin) {
            unsigned long long m = __ballot(g == bin);
            if (g == bin) pos = starts[bin] + running[bin] + (int)__popcll(m & lt);
            running[bin] += (int)__popcll(m);
        }
        perm[b * S_ + pos] = i;
    }
}

// ---- Wstack[h][bi][kt][D][kk] = W2_[c(bi,g),h,d,D], B-frag swizzled bf16; fp32 in ----
// k = g*64+d in [0,320), kt = k>>5, kk = k&31.
__global__ void k_w2s(const float* __restrict__ W2, const float* __restrict__ al,
                      u16* __restrict__ Wst) {
    const int h = blockIdx.x / NG_, bi = blockIdx.x % NG_;
    float sm[NG_][NMB_];
#pragma unroll
    for (int g = 0; g < NG_; ++g) {
        int c = (bi == 0 || g == 0) ? 0 : (bi - 1) * NMB_ + g;
        float a[NMB_]; float mx = -1e30f;
#pragma unroll
        for (int m = 0; m < NMB_; ++m) { a[m] = al[(c * NMB_ + m) * H_ + h]; mx = fmaxf(mx, a[m]); }
        float s = 0.f;
#pragma unroll
        for (int m = 0; m < NMB_; ++m) { a[m] = __expf(a[m] - mx); s += a[m]; }
        float inv = 1.f / s;
#pragma unroll
        for (int m = 0; m < NMB_; ++m) sm[g][m] = a[m] * inv;
    }
    for (int e = threadIdx.x; e < 320 * 64; e += 256) {
        int k = e >> 6, D = e & 63;
        int g = k >> 6, d = k & 63;
        float acc = 0.f;
#pragma unroll
        for (int m = 0; m < NMB_; ++m)
            acc += sm[g][m] * W2[((m * H_ + h) * K_ + d) * K_ + D];
        int kt = k >> 5, kk = k & 31;
        Wst[(((h * NG_ + bi) * 10 + kt) * 64 + D) * 32 + kk] = f2b(acc);
    }
}

// ---- M_frag[b][h][kt][n][kk] = (b_seq[j]==g ? v[j,d] : 0), B-frag swizzled bf16; fp32 in ----
// Coalesced-write version: thread <-> one 16 B kk-chunk, consecutive threads -> consecutive
// addresses. c = tid&3 is iteration-invariant -> the 8 group-ids hoist out of the loop.
__global__ void k_buildM(const float* __restrict__ V, const int* __restrict__ b_seq,
                         u16* __restrict__ Mf) {
    const int kt = blockIdx.x, h = blockIdx.y, b = blockIdx.z;
    const int bh = b * H_ + h;
    const int tid = threadIdx.x;             // 256
    const int c = tid & 3;                   // kk-chunk: kk = c*8 + q

    int gj[8];
#pragma unroll
    for (int q = 0; q < 8; ++q)
        gj[q] = clamp5(b_seq[b * S_ + kt * 32 + c * 8 + q]);   // L1-hot 128 B

#pragma unroll
    for (int it = 0; it < 5; ++it) {
        const int u = it * 256 + tid;        // 0..1279
        const int n = u >> 2;                // 0..319
        const int g = n >> 6, d = n & 63;
        u16 o[8];
#pragma unroll
        for (int q = 0; q < 8; ++q) {
            int j = kt * 32 + c * 8 + q;
            float v = V[((size_t)bh * S_ + j) * K_ + d];
            o[q] = (gj[q] == g) ? f2b(v) : (u16)0;
        }
        uint4 w;
        w.x = (uint32_t)o[0] | ((uint32_t)o[1] << 16);
        w.y = (uint32_t)o[2] | ((uint32_t)o[3] << 16);
        w.z = (uint32_t)o[4] | ((uint32_t)o[5] << 16);
        w.w = (uint32_t)o[6] | ((uint32_t)o[7] << 16);
        // byte addr = ((bh*16+kt)*320 + n)*64 + c*16  -> consecutive per consecutive tid
        *reinterpret_cast<uint4*>(Mf + (((size_t)bh * 16 + kt) * 320 + n) * 32 + c * 8) = w;
    }
}

// ---- fused: stmp = P@M (MFMA) -> LDS -> out = stmp@Wstack[bi] (MFMA) ----
// nt-split: 2 waves per 16-row tile; wave `half` owns stage-1 nt = half*10..+10
// and stage-2 nt = half*2..+2. Block = 4 waves = 2 tiles. Grid 16x8x8.
__global__ __launch_bounds__(256) void k_main(const float* __restrict__ P,
                                              const int* __restrict__ b_seq,
                                              const int* __restrict__ perm,
                                              const u16* __restrict__ Mf,
                                              const u16* __restrict__ Wst,
                                              float* __restrict__ out) {
    __shared__ __align__(16) u16 smem[2][16 * 328];  // per-tile 16x320 bf16 tile, +8 pad
    const int b = blockIdx.z, h = blockIdx.y;
    const int ty = threadIdx.y;                      // 0..3
    const int tl = ty >> 1;                          // tile within block
    const int half = ty & 1;                         // nt-split half
    const int lane = threadIdx.x;
    const int r16 = lane & 15, quad = lane >> 4;
    const int tile = blockIdx.x * 2 + tl;            // 0..31
    const int bh = b * H_ + h;

    // gathered rows (sorted by bi); lane L holds row L&15
    const int vi  = perm[b * S_ + tile * 16 + r16] & (S_ - 1);
    const int vbi = clamp5(b_seq[b * S_ + vi]);

    // ---- stage 1: acc1[ntl] (16 x 160) = P[rows, :] @ M[:, half*160..] ----
    f32x4 acc1[10];
#pragma unroll
    for (int ntl = 0; ntl < 10; ++ntl) acc1[ntl] = (f32x4){0.f, 0.f, 0.f, 0.f};

    // A[m=r16][k = kt*32 + quad*8 + j], fp32 -> bf16 cvt in-register
    const float* aP = P + ((size_t)bh * S_ + vi) * S_ + quad * 8;
    for (int kt = 0; kt < 16; ++kt) {
        float4 x = *reinterpret_cast<const float4*>(aP + kt * 32);
        float4 y = *reinterpret_cast<const float4*>(aP + kt * 32 + 4);
        short8 afrag;
        afrag[0] = (short)f2b(x.x); afrag[1] = (short)f2b(x.y);
        afrag[2] = (short)f2b(x.z); afrag[3] = (short)f2b(x.w);
        afrag[4] = (short)f2b(y.x); afrag[5] = (short)f2b(y.y);
        afrag[6] = (short)f2b(y.z); afrag[7] = (short)f2b(y.w);
        const u16* mb = Mf + (((size_t)bh * 16 + kt) * 320 + r16) * 32 + quad * 8
                        + (size_t)(half * 10) * 16 * 32;
#pragma unroll
        for (int ntl = 0; ntl < 10; ++ntl) {
            short8 bfrag = ld16(mb + (size_t)ntl * 16 * 32);
            acc1[ntl] = __builtin_amdgcn_mfma_f32_16x16x32_bf16(afrag, bfrag, acc1[ntl], 0, 0, 0);
        }
    }

    // ---- C-layout -> A-layout via LDS (bf16 cast); each wave writes its 10 nt cols ----
    u16* st = smem[tl];
#pragma unroll
    for (int ntl = 0; ntl < 10; ++ntl) {
        int nt = half * 10 + ntl;
#pragma unroll
        for (int r = 0; r < 4; ++r) {
            int row = quad * 4 + r;                  // C/D: row=(lane>>4)*4+reg, col=lane&15
            st[row * 328 + nt * 16 + r16] = f2b(acc1[ntl][r]);
        }
    }
    __syncthreads();

    // ---- stage 2: out rows = stmp_tile @ Wstack[blk]; wave does nt = half*2..+2 ----
    int blo = __shfl(vbi, 0), bhi = __shfl(vbi, 15);   // sorted => contiguous classes
    if (bhi < blo) bhi = blo;
    for (int blk = blo; blk <= bhi; ++blk) {
        f32x4 acc2[2];
#pragma unroll
        for (int ntl = 0; ntl < 2; ++ntl) acc2[ntl] = (f32x4){0.f, 0.f, 0.f, 0.f};
        const u16* wb = Wst + ((size_t)(h * NG_ + blk) * 10) * (64 * 32) + r16 * 32 + quad * 8
                        + (size_t)(half * 2) * 16 * 32;
        for (int kt = 0; kt < 10; ++kt) {
            short8 a2 = *reinterpret_cast<const short8*>(&st[r16 * 328 + kt * 32 + quad * 8]);
#pragma unroll
            for (int ntl = 0; ntl < 2; ++ntl) {
                short8 b2 = ld16(wb + kt * (64 * 32) + ntl * 16 * 32);
                acc2[ntl] = __builtin_amdgcn_mfma_f32_16x16x32_bf16(a2, b2, acc2[ntl], 0, 0, 0);
            }
        }
#pragma unroll
        for (int r = 0; r < 4; ++r) {
            int row = quad * 4 + r;
            int bir = __shfl(vbi, row);
            int ir  = __shfl(vi, row);
            if (bir == blk) {
#pragma unroll
                for (int ntl = 0; ntl < 2; ++ntl) {
                    int nt = half * 2 + ntl;
                    out[((size_t)bh * S_ + ir) * K_ + nt * 16 + r16] = acc2[ntl][r];
                }
            }
        }
    }
}

// ---------------- launcher ----------------
extern "C" void kernel_launch(void* const* d_in, const int* in_sizes, int n_in,
                              void* d_out, int out_size, void* d_ws, size_t ws_size,
                              hipStream_t stream) {
    const float* p_attn = (const float*)d_in[0];
    const float* value  = (const float*)d_in[1];
    const int*   b_seq  = (const int*)d_in[2];
    const float* W2     = (const float*)d_in[3];
    const float* alpha2 = (const float*)d_in[4];

    char* ws = (char*)d_ws;
    int* perm = (int*)(ws + OFF_PERM);
    u16* Wst  = (u16*)(ws + OFF_WST);
    u16* Mf   = (u16*)(ws + OFF_MF);

    hipLaunchKernelGGL(k_sort, dim3(B_), dim3(64), 0, stream, b_seq, perm);
    hipLaunchKernelGGL(k_w2s, dim3(H_ * NG_), dim3(256), 0, stream, W2, alpha2, Wst);
    hipLaunchKernelGGL(k_buildM, dim3(16, H_, B_), dim3(256), 0, stream, value, b_seq, Mf);
    hipLaunchKernelGGL(k_main, dim3(16, H_, B_), dim3(64, 4), 0, stream,
                       p_attn, b_seq, perm, Mf, Wst, (float*)d_out);
}